// Round 11
// baseline (299.123 us; speedup 1.0000x reference)
//
#include <hip/hip_runtime.h>
#include <cmath>

#define NN 50000
#define NE 800000
#define INF_ 128
#define NR 64
#define OF 128
#define TS 256
#define NT ((NN + TS - 1) / TS)  // 196 tiles

__device__ __forceinline__ unsigned short f2bf_rne(float f) {
  unsigned u = __float_as_uint(f);
  u += 0x7FFFu + ((u >> 16) & 1u);  // round-to-nearest-even
  return (unsigned short)(u >> 16);
}

// zero cnt[]; block 0 also computes q3[d] = sum_j W[(256+d),j] * a[j]
__global__ void k_init(const float* __restrict__ W, const float* __restrict__ a,
                       float* __restrict__ q3, int* __restrict__ cnt) {
  int i = blockIdx.x * 256 + threadIdx.x;
  if (i < NN) cnt[i] = 0;
  if (blockIdx.x == 0 && threadIdx.x < NR) {
    const float* row = W + (size_t)(2 * INF_ + threadIdx.x) * OF;
    float acc = 0.f;
    for (int j = 0; j < OF; ++j) acc = fmaf(row[j], a[j], acc);
    q3[threadIdx.x] = acc;
  }
}

// per-node precompute: xW1 = x@W1 (fp32), xw2h = x@W2 (bf16), p1, p2.
// Fused: src-degree histogram (grid*block == NE exactly, one edge per thread).
__global__ void k_node_pre(const float* __restrict__ x, const float* __restrict__ W,
                           const float* __restrict__ a, const int* __restrict__ ei,
                           float* __restrict__ xW1, unsigned short* __restrict__ xw2h,
                           float* __restrict__ p1, float* __restrict__ p2,
                           int* __restrict__ cnt) {
  int gid = blockIdx.x * 128 + threadIdx.x;  // 0..799999 == edge id
  atomicAdd(cnt + ei[gid], 1);
  __shared__ float xs[8][INF_];
  __shared__ float red[2][2][8];
  int nb = blockIdx.x * 8;
  int o = threadIdx.x;  // 0..127
  for (int t = 0; t < 8; ++t) xs[t][o] = x[(size_t)(nb + t) * INF_ + o];
  __syncthreads();
  float acc1[8] = {0.f, 0.f, 0.f, 0.f, 0.f, 0.f, 0.f, 0.f};
  float acc2[8] = {0.f, 0.f, 0.f, 0.f, 0.f, 0.f, 0.f, 0.f};
  for (int k = 0; k < INF_; ++k) {
    float w1 = W[(size_t)k * OF + o];
    float w2 = W[(size_t)(INF_ + k) * OF + o];
#pragma unroll
    for (int t = 0; t < 8; ++t) {
      acc1[t] = fmaf(xs[t][k], w1, acc1[t]);
      acc2[t] = fmaf(xs[t][k], w2, acc2[t]);
    }
  }
  float av = a[o];
  int wv = o >> 6, ln = o & 63;
#pragma unroll
  for (int t = 0; t < 8; ++t) {
    xW1[(size_t)(nb + t) * OF + o] = acc1[t];
    xw2h[(size_t)(nb + t) * OF + o] = f2bf_rne(acc2[t]);
    float v1 = acc1[t] * av, v2 = acc2[t] * av;
    for (int off = 32; off > 0; off >>= 1) {
      v1 += __shfl_down(v1, off, 64);
      v2 += __shfl_down(v2, off, 64);
    }
    if (ln == 0) { red[0][wv][t] = v1; red[1][wv][t] = v2; }
  }
  __syncthreads();
  if (o < 8) {
    p1[nb + o] = red[0][0][o] + red[0][1][o];
    p2[nb + o] = red[1][0][o] + red[1][1][o];
  }
}

// hierarchical scan, phase A: coalesced per-tile exclusive scan + tile sums
__global__ void k_scanA(const int* __restrict__ cnt, int* __restrict__ roff,
                        int* __restrict__ tsum) {
  __shared__ int sh[TS];
  int b = blockIdx.x, t = threadIdx.x;
  int i = b * TS + t;
  int v = (i < NN) ? cnt[i] : 0;
  sh[t] = v;
  __syncthreads();
  for (int off = 1; off < TS; off <<= 1) {
    int u = (t >= off) ? sh[t - off] : 0;
    __syncthreads();
    sh[t] += u;
    __syncthreads();
  }
  if (i < NN) roff[i] = sh[t] - v;  // exclusive within tile
  if (t == TS - 1) tsum[b] = sh[t];
}

// phase B: every block redundantly LDS-scans the 196 tile sums, adds its
// tile offset, and writes roff (+cur copy); last block sets roff[NN]=NE.
__global__ void k_scanB(const int* __restrict__ tsum, int* __restrict__ roff,
                        int* __restrict__ cur) {
  __shared__ int sh[256];
  int b = blockIdx.x, t = threadIdx.x;
  sh[t] = (t < NT) ? tsum[t] : 0;
  __syncthreads();
  for (int off = 1; off < 256; off <<= 1) {
    int u = (t >= off) ? sh[t - off] : 0;
    __syncthreads();
    sh[t] += u;
    __syncthreads();
  }
  int toff = (b == 0) ? 0 : sh[b - 1];
  int i = b * TS + t;
  if (i < NN) {
    int r = roff[i] + toff;
    roff[i] = r;
    cur[i] = r;
  }
  if (b == NT - 1 && t == 0) roff[NN] = NE;
}

// scatter (edge id, dst) + p2[dst] into CSR slots. The p2 gather lives here
// (800K-thread parallelism hides the random 4B reads).
__global__ void k_scatter(const int* __restrict__ ei, const float* __restrict__ p2,
                          int* __restrict__ cur, int2* __restrict__ es,
                          float* __restrict__ wpv) {
  int e = blockIdx.x * blockDim.x + threadIdx.x;
  if (e < NE) {
    int dst = ei[NE + e];
    int pos = atomicAdd(cur + ei[e], 1);
    es[pos] = make_int2(e, dst);
    wpv[pos] = p2[dst];
  }
}

// fused gather+finalize: TWO nodes per wave, no LDS, no barrier.
// Main loop (proven round-9 structure): per edge, logit = p1[n]+pv+ete·q3
// (64-lane butterfly), ev = exp(leaky_relu); accumulate ssum, ev*ete,
// ev*xW2(bf16) unnormalized. Epilogue is WAVE-LOCAL (round-6 lesson: block
// barrier couples waves of different degree; round-7 lesson: full unroll of
// the d-loop spills -> pin unroll 4): g@W3 via shfl broadcast of each lane's
// g element, + sa*xW1 + normalized o, ELU, single out store.
__global__ void __launch_bounds__(256, 4)
k_gather(const int2* __restrict__ es, const float* __restrict__ wpv,
         const int* __restrict__ roff, const float* __restrict__ ete,
         const unsigned short* __restrict__ xw2h,
         const float* __restrict__ q3, const float* __restrict__ p1,
         const float* __restrict__ xW1, const float* __restrict__ W,
         float* __restrict__ out) {
  int wv = blockIdx.x * 4 + (threadIdx.x >> 6);  // wave id; grid exact
  int nA = wv * 2, nB = nA + 1;
  int l = threadIdx.x & 63;
  float q3l = q3[l];
  int begA = roff[nA], endA = roff[nA + 1], endB = roff[nB + 1];
  float p1A = p1[nA], p1B = p1[nB];
  float ssA = 0.f, gaA = 0.f, oA0 = 0.f, oA1 = 0.f;
  float ssB = 0.f, gaB = 0.f, oB0 = 0.f, oB1 = 0.f;
  int jbA = begA, jbB = endA;  // begB == endA (CSR contiguity)
  while (jbA < endA || jbB < endB) {
    int2 edA = make_int2(0, 0), edB = make_int2(0, 0);
    float pvA = -INFINITY, pvB = -INFINITY;
    if (jbA + l < endA) { edA = es[jbA + l]; pvA = wpv[jbA + l]; }
    if (jbB + l < endB) { edB = es[jbB + l]; pvB = wpv[jbB + l]; }
    int mA = endA - jbA; mA = mA < 0 ? 0 : (mA > 64 ? 64 : mA);
    int mB = endB - jbB; mB = mB < 0 ? 0 : (mB > 64 ? 64 : mB);
    int mm = mA > mB ? mA : mB;
    for (int jj = 0; jj < mm; jj += 4) {
#pragma unroll
      for (int q = 0; q < 4; ++q) {
        // jj+q <= 63 always; lanes beyond a node's m hold pv=-inf -> ev=0
        int eA = __shfl(edA.x, jj + q, 64);
        int dA = __shfl(edA.y, jj + q, 64);
        float pA = __shfl(pvA, jj + q, 64);
        int eB = __shfl(edB.x, jj + q, 64);
        int dB = __shfl(edB.y, jj + q, 64);
        float pB = __shfl(pvB, jj + q, 64);
        float tA = ete[(size_t)eA * NR + l];
        float tB = ete[(size_t)eB * NR + l];
        unsigned uA = *(const unsigned*)(xw2h + (size_t)dA * OF + 2 * l);
        unsigned uB = *(const unsigned*)(xw2h + (size_t)dB * OF + 2 * l);
        float xA0 = __uint_as_float(uA << 16);
        float xA1 = __uint_as_float(uA & 0xFFFF0000u);
        float xB0 = __uint_as_float(uB << 16);
        float xB1 = __uint_as_float(uB & 0xFFFF0000u);
        float dsA = tA * q3l, dsB = tB * q3l;
        dsA += __shfl_xor(dsA, 1, 64);  dsB += __shfl_xor(dsB, 1, 64);
        dsA += __shfl_xor(dsA, 2, 64);  dsB += __shfl_xor(dsB, 2, 64);
        dsA += __shfl_xor(dsA, 4, 64);  dsB += __shfl_xor(dsB, 4, 64);
        dsA += __shfl_xor(dsA, 8, 64);  dsB += __shfl_xor(dsB, 8, 64);
        dsA += __shfl_xor(dsA, 16, 64); dsB += __shfl_xor(dsB, 16, 64);
        dsA += __shfl_xor(dsA, 32, 64); dsB += __shfl_xor(dsB, 32, 64);
        float vA = p1A + pA + dsA;
        float vB = p1B + pB + dsB;
        vA = vA > 0.f ? vA : 0.2f * vA;
        vB = vB > 0.f ? vB : 0.2f * vB;
        float eVA = __expf(vA);
        float eVB = __expf(vB);
        ssA += eVA;               ssB += eVB;
        gaA = fmaf(eVA, tA, gaA); gaB = fmaf(eVB, tB, gaB);
        oA0 = fmaf(eVA, xA0, oA0); oB0 = fmaf(eVB, xB0, oB0);
        oA1 = fmaf(eVA, xA1, oA1); oB1 = fmaf(eVB, xB1, oB1);
      }
    }
    jbA += 64; jbB += 64;
  }
  // wave-local finalize (no barrier): lane l holds g[n][l] normalized
  float invA = 1.f / (ssA + 1e-16f);
  float invB = 1.f / (ssB + 1e-16f);
  float saA = ssA * invA, saB = ssB * invB;
  float gnA = gaA * invA, gnB = gaB * invB;
  const float* W3 = W + (size_t)(2 * INF_) * OF;
  float aA0 = 0.f, aA1 = 0.f, aB0 = 0.f, aB1 = 0.f;
#pragma unroll 4
  for (int d = 0; d < NR; ++d) {
    float2 w3 = *(const float2*)(W3 + (size_t)d * OF + 2 * l);
    float gdA = __shfl(gnA, d, 64);
    float gdB = __shfl(gnB, d, 64);
    aA0 = fmaf(gdA, w3.x, aA0); aA1 = fmaf(gdA, w3.y, aA1);
    aB0 = fmaf(gdB, w3.x, aB0); aB1 = fmaf(gdB, w3.y, aB1);
  }
  float2 x1A = *(const float2*)(xW1 + (size_t)nA * OF + 2 * l);
  float2 x1B = *(const float2*)(xW1 + (size_t)nB * OF + 2 * l);
  float vA0 = fmaf(saA, x1A.x, fmaf(oA0, invA, aA0));
  float vA1 = fmaf(saA, x1A.y, fmaf(oA1, invA, aA1));
  float vB0 = fmaf(saB, x1B.x, fmaf(oB0, invB, aB0));
  float vB1 = fmaf(saB, x1B.y, fmaf(oB1, invB, aB1));
  vA0 = vA0 > 0.f ? vA0 : expm1f(vA0);
  vA1 = vA1 > 0.f ? vA1 : expm1f(vA1);
  vB0 = vB0 > 0.f ? vB0 : expm1f(vB0);
  vB1 = vB1 > 0.f ? vB1 : expm1f(vB1);
  *(float2*)(out + (size_t)nA * OF + 2 * l) = make_float2(vA0, vA1);
  *(float2*)(out + (size_t)nB * OF + 2 * l) = make_float2(vB0, vB1);
}

extern "C" void kernel_launch(void* const* d_in, const int* in_sizes, int n_in,
                              void* d_out, int out_size, void* d_ws, size_t ws_size,
                              hipStream_t stream) {
  const int* ei = (const int*)d_in[0];
  const float* x = (const float*)d_in[1];
  const float* ete = (const float*)d_in[2];
  const float* W = (const float*)d_in[3];
  const float* a = (const float*)d_in[4];
  float* out = (float*)d_out;

  float* ws = (float*)d_ws;
  float* xW1 = ws;                                      // N*128 fp32 (6.4M words)
  unsigned short* xw2h = (unsigned short*)(xW1 + (size_t)NN * OF);  // N*128 bf16 (3.2M words)
  int2* es = (int2*)(xW1 + (size_t)NN * OF + (size_t)NN * OF / 2);  // E int2 (word off 9.6M, even)
  float* wpv = (float*)(es + NE);                       // E
  float* p1 = wpv + NE;                                 // N
  float* p2 = p1 + NN;                                  // N
  float* q3 = p2 + NN;                                  // 64
  int* cnt = (int*)(q3 + NR);                           // N
  int* roff = cnt + NN;                                 // N+1
  int* cur = roff + NN + 1;                             // N
  int* tsum = cur + NN;                                 // 256
  // total ~13M words = 52 MB

  k_init<<<(NN + 255) / 256, 256, 0, stream>>>(W, a, q3, cnt);
  k_node_pre<<<NN / 8, 128, 0, stream>>>(x, W, a, ei, xW1, xw2h, p1, p2, cnt);
  k_scanA<<<NT, TS, 0, stream>>>(cnt, roff, tsum);
  k_scanB<<<NT, 256, 0, stream>>>(tsum, roff, cur);
  k_scatter<<<NE / 256, 256, 0, stream>>>(ei, p2, cur, es, wpv);
  k_gather<<<NN / 8, 256, 0, stream>>>(es, wpv, roff, ete, xw2h, q3, p1, xW1, W, out);
}